// Round 3
// baseline (362.687 us; speedup 1.0000x reference)
//
#include <hip/hip_runtime.h>

#define FM_C 256
#define FM_H 200
#define FM_W 336
#define CROP 14
#define NSAMP (CROP * CROP)      // 196 spatial samples per (m,c); 196 % 4 == 0
#define HW (FM_H * FM_W)         // 67200
#define CPB 64                   // channels per block
#define THREADS 256

__device__ __forceinline__ float bilerp(const float* __restrict__ p,
                                        int otl, int otr, int obl, int obr,
                                        float xf, float yf, float mk)
{
    const float tl = p[otl], tr = p[otr], bl = p[obl], br = p[obr];
    // Reference op order, unfused (XLA f32 semantics): top = tl + (tr-tl)*xf, etc.
    const float top = __fadd_rn(tl, __fmul_rn(__fsub_rn(tr, tl), xf));
    const float bot = __fadd_rn(bl, __fmul_rn(__fsub_rn(br, bl), xf));
    const float o   = __fadd_rn(top, __fmul_rn(__fsub_rn(bot, top), yf));
    return __fmul_rn(o, mk);     // mk = 1.0 (exact) or 0.0 (extrapolation value)
}

__global__ __launch_bounds__(THREADS)
void roialign_kernel(const float* __restrict__ fm,
                     const float* __restrict__ boxes,
                     const int* __restrict__ box_ind,
                     float* __restrict__ out)
{
    __shared__ __align__(16) float s_xf[NSAMP], s_yf[NSAMP], s_mk[NSAMP];
    __shared__ __align__(16) int   s_tl[NSAMP], s_tr[NSAMP], s_bl[NSAMP], s_br[NSAMP];

    const int m  = blockIdx.x;        // box index
    const int cg = blockIdx.y;        // channel group
    const int t  = threadIdx.x;

    // ---- Phase 1: per-sample interpolation parameters -> LDS (once per block) ----
    if (t < NSAMP) {
        const float bx1 = boxes[4 * m + 0];
        const float by1 = boxes[4 * m + 1];
        const float bx2 = boxes[4 * m + 2];
        const float by2 = boxes[4 * m + 3];

        // Replicate reference op-for-op in f32 (no FMA contraction):
        const float spacing_w = __fdiv_rn(__fsub_rn(bx2, bx1), 14.0f);
        const float spacing_h = __fdiv_rn(__fsub_rn(by2, by1), 14.0f);
        const float nx0 = __fdiv_rn(__fsub_rn(__fadd_rn(bx1, __fdiv_rn(spacing_w, 2.0f)), 0.5f), 335.0f);
        const float ny0 = __fdiv_rn(__fsub_rn(__fadd_rn(by1, __fdiv_rn(spacing_h, 2.0f)), 0.5f), 199.0f);
        const float nw  = __fdiv_rn(__fmul_rn(spacing_w, 13.0f), 335.0f);
        // NOTE: reference quirk — nh uses spacing_w, not spacing_h. Must match.
        const float nh  = __fdiv_rn(__fmul_rn(spacing_w, 13.0f), 199.0f);

        const float y1n = ny0, x1n = nx0;
        const float y2n = __fadd_rn(ny0, nh);
        const float x2n = __fadd_rn(nx0, nw);

        const int i = t / CROP;
        const int j = t % CROP;

        const float step_y = __fdiv_rn(__fmul_rn(__fsub_rn(y2n, y1n), 199.0f), 13.0f);
        const float step_x = __fdiv_rn(__fmul_rn(__fsub_rn(x2n, x1n), 335.0f), 13.0f);
        const float in_y = __fadd_rn(__fmul_rn(y1n, 199.0f), __fmul_rn((float)i, step_y));
        const float in_x = __fadd_rn(__fmul_rn(x1n, 335.0f), __fmul_rn((float)j, step_x));

        const bool valid = (in_y >= 0.0f) && (in_y <= 199.0f) &&
                           (in_x >= 0.0f) && (in_x <= 335.0f);

        const float y0f = floorf(in_y);
        const float x0f = floorf(in_x);
        const int y0i = (int)fminf(fmaxf(y0f, 0.0f), 199.0f);
        const int y1i = (int)fminf(fmaxf(__fadd_rn(y0f, 1.0f), 0.0f), 199.0f);
        const int x0i = (int)fminf(fmaxf(x0f, 0.0f), 335.0f);
        const int x1i = (int)fminf(fmaxf(__fadd_rn(x0f, 1.0f), 0.0f), 335.0f);

        s_xf[t] = __fsub_rn(in_x, x0f);
        s_yf[t] = __fsub_rn(in_y, y0f);
        s_mk[t] = valid ? 1.0f : 0.0f;
        s_tl[t] = y0i * FM_W + x0i;
        s_tr[t] = y0i * FM_W + x1i;
        s_bl[t] = y1i * FM_W + x0i;
        s_br[t] = y1i * FM_W + x1i;
    }
    __syncthreads();

    // ---- Phase 2: all 256 lanes sweep the block's (CPB x NSAMP) tile in float4s ----
    const int b = box_ind[m];
    const float* __restrict__ plane = fm  + ((size_t)b * FM_C + (size_t)cg * CPB) * HW;
    float*       __restrict__ outp  = out + ((size_t)m * FM_C + (size_t)cg * CPB) * NSAMP;

    const int NG = CPB * NSAMP / 4;   // 3136 float4 groups; 49 groups per channel
    for (int g = t; g < NG; g += THREADS) {
        const int c  = g / 49;                 // channel within group (magic-mul)
        const int s0 = (g - c * 49) * 4;       // sample start, multiple of 4

        const float4 xf = *(const float4*)&s_xf[s0];
        const float4 yf = *(const float4*)&s_yf[s0];
        const float4 mk = *(const float4*)&s_mk[s0];
        const int4   tl = *(const int4*)&s_tl[s0];
        const int4   tr = *(const int4*)&s_tr[s0];
        const int4   bl = *(const int4*)&s_bl[s0];
        const int4   br = *(const int4*)&s_br[s0];

        const float* __restrict__ pc = plane + (size_t)c * HW;
        float4 r;
        r.x = bilerp(pc, tl.x, tr.x, bl.x, br.x, xf.x, yf.x, mk.x);
        r.y = bilerp(pc, tl.y, tr.y, bl.y, br.y, xf.y, yf.y, mk.y);
        r.z = bilerp(pc, tl.z, tr.z, bl.z, br.z, xf.z, yf.z, mk.z);
        r.w = bilerp(pc, tl.w, tr.w, bl.w, br.w, xf.w, yf.w, mk.w);

        *(float4*)&outp[4 * g] = r;            // 16 B/lane coalesced store
    }
}

extern "C" void kernel_launch(void* const* d_in, const int* in_sizes, int n_in,
                              void* d_out, int out_size, void* d_ws, size_t ws_size,
                              hipStream_t stream) {
    const float* fm      = (const float*)d_in[0];
    const float* boxes   = (const float*)d_in[1];
    const int*   box_ind = (const int*)d_in[2];
    float*       out     = (float*)d_out;

    const int M = in_sizes[2];            // number of boxes (1024)

    dim3 grid(M, FM_C / CPB);             // (1024, 4)
    roialign_kernel<<<grid, THREADS, 0, stream>>>(fm, boxes, box_ind, out);
}